// Round 3
// baseline (93.663 us; speedup 1.0000x reference)
//
#include <hip/hip_runtime.h>
#include <hip/hip_bf16.h>
#include <math.h>

// Problem constants (fixed by reference setup_inputs)
#define B_SZ 64
#define N_IN 1024
#define IDIM 64
#define NC   16
#define DC   32

// Workspace layout (floats). NOTHING needs zero-init: every region is fully
// written before read (partials scheme, no atomics, no memset).
//  xsump : [64][8][64]       @ 0          (colsum partials per 128-row chunk)
//  xs1p  : [64][16][16][64]  @ 32768      (xs partials per 64-row chunk)
//  xs2p  : [64][16][16][64]  @ 1081344
//  blog  : [64][16][1024]    @ 2129920
#define WS_XSUMP 0
#define WS_XS1P  32768
#define WS_XS2P  1081344
#define WS_BLOG  2129920

// -------- Kernel 1: column-sum partials: xsump[b][chunk][i] = sum_{n in chunk} x[b,n,i]
__global__ __launch_bounds__(256) void k_colsum(const float* __restrict__ x,
                                                float* __restrict__ xsump) {
    const int b = blockIdx.y, chunk = blockIdx.x;          // 8 chunks of 128 rows
    const int i = threadIdx.x & 63, p = threadIdx.x >> 6;  // 4-way row split
    const float* xb = x + (size_t)(b * N_IN + chunk * 128) * IDIM;
    float s = 0.f;
    for (int r = p; r < 128; r += 4) s += xb[r * IDIM + i];  // coalesced 1KB/instr
    __shared__ float red[4][64];
    red[p][i] = s;
    __syncthreads();
    if (p == 0)
        xsump[(b * 8 + chunk) * 64 + i] = red[0][i] + red[1][i] + red[2][i] + red[3][i];
}

// -------- Kernel 2/3 (heavy, fused): per (b, 64-row chunk), 256 threads = 4 waves.
//  Prologue (redundant per chunk): reduce prev-stage partials -> s -> squash v -> wv (LDS)
//  Phase 2: a[c][n] = x[n].wv[c]  (wave g handles caps 4g..4g+3, lane = n)
//  blog store (ITER1) / load+add (ITER2); softmax over c in-register per lane
//  Phase 3: wave g accumulates 16 rows into acc[16] (lane = i), in-block reduce,
//  write one partial [16c][64i] per block.
template<int ITER>
__global__ __launch_bounds__(256) void k_route(const float* __restrict__ x,
                                               const float* __restrict__ W,
                                               const float* __restrict__ partIn,
                                               float* __restrict__ blog,
                                               float* __restrict__ partOut) {
    const int b = blockIdx.y, chunk = blockIdx.x;   // 16 chunks of 64 rows
    const int tid = threadIdx.x, lane = tid & 63, wave = tid >> 6;

    __shared__ float xT[64 * 64];     // 16 KB; skewed transpose; aliased as pSm at the end
    __shared__ float wvSm[NC * 64];   // 4 KB
    __shared__ float scr[2048];       // 8 KB: prologue {redSm 4K | vSm 2K}, later {aSm 4K | cwSm 4K}
    float* redSm = scr;               // ITER1: [64]; ITER2: [16][64]
    float* vSm   = scr + 1024;        // [16][32]
    float* aSm   = scr;               // [16][64]
    float* cwSm  = scr + 1024;        // [16][64]

    // ---- issue x loads early (hide HBM latency under prologue) ----
    const float4* xb4 = reinterpret_cast<const float4*>(x + (size_t)(b * N_IN + chunk * 64) * IDIM);
    float4 xreg[4];
#pragma unroll
    for (int m = 0; m < 4; m++) xreg[m] = xb4[tid + m * 256];

    // ---- prologue: reduce partials ----
    if (ITER == 1) {
        if (tid < 64) {
            float r = 0.f;
#pragma unroll
            for (int k = 0; k < 8; k++) r += partIn[(b * 8 + k) * 64 + tid];
            redSm[tid] = r;
        }
    } else {
        for (int o = tid; o < NC * 64; o += 256) {
            float r = 0.f;
#pragma unroll
            for (int k = 0; k < 16; k++) r += partIn[((size_t)(b * 16 + k) * NC) * 64 + o];
            redSm[o] = r;
        }
    }
    __syncthreads();
    // ---- s = red @ W[c], squash -> vSm ----
    {
        const int d = tid & 31, cg = tid >> 5;   // cg 0..7
#pragma unroll
        for (int h = 0; h < 2; h++) {
            const int c = cg + h * 8;
            const float* Wc = W + c * IDIM * DC;
            float s = 0.f;
#pragma unroll 8
            for (int i = 0; i < IDIM; i++)
                s += ((ITER == 1) ? redSm[i] : redSm[c * 64 + i]) * Wc[i * DC + d];
            if (ITER == 1) s *= (1.f / 16.f);
            float n2 = s * s;
#pragma unroll
            for (int m = 16; m >= 1; m >>= 1) n2 += __shfl_xor(n2, m);  // within 32-lane half
            const float nr = sqrtf(n2);
            vSm[c * 32 + d] = (n2 / (1.f + n2)) * s / (nr + 1e-8f);
        }
    }
    __syncthreads();
    // ---- wv[c][i] = W[c] @ v -> wvSm ----
    {
        const int i = tid & 63, cq = tid >> 6;
#pragma unroll
        for (int h = 0; h < 4; h++) {
            const int c = cq + h * 4;
            const float* Wci = W + (c * IDIM + i) * DC;
            float w = 0.f;
#pragma unroll 8
            for (int d = 0; d < DC; d++) w += Wci[d] * vSm[c * 32 + d];
            wvSm[c * 64 + i] = w;
        }
    }
    // ---- write x chunk to skewed LDS: (n,i) at xT[i*64 + ((n+i)&63)] ----
#pragma unroll
    for (int m = 0; m < 4; m++) {
        const int f = tid + m * 256, nl = f >> 4, i0 = (f & 15) * 4;
        const float vv[4] = {xreg[m].x, xreg[m].y, xreg[m].z, xreg[m].w};
#pragma unroll
        for (int j = 0; j < 4; j++) {
            const int i = i0 + j;
            xT[i * 64 + ((nl + i) & 63)] = vv[j];
        }
    }
    __syncthreads();

    // ---- phase 2: agreement. wave g -> caps 4g..4g+3, lane = n' ----
    {
        float a[4] = {0.f, 0.f, 0.f, 0.f};
#pragma unroll 4
        for (int i = 0; i < IDIM; i++) {
            const float xv = xT[i * 64 + ((lane + i) & 63)];
#pragma unroll
            for (int cc = 0; cc < 4; cc++) a[cc] += xv * wvSm[(wave * 4 + cc) * 64 + i];
        }
        const int n = chunk * 64 + lane;
        float* bl = blog + (size_t)b * NC * N_IN;
        if (ITER == 2) {
#pragma unroll
            for (int cc = 0; cc < 4; cc++) a[cc] += bl[(wave * 4 + cc) * N_IN + n];
        } else {
#pragma unroll
            for (int cc = 0; cc < 4; cc++) bl[(wave * 4 + cc) * N_IN + n] = a[cc];
        }
#pragma unroll
        for (int cc = 0; cc < 4; cc++) aSm[(wave * 4 + cc) * 64 + lane] = a[cc];
    }
    __syncthreads();
    // ---- softmax over 16 caps per n (each wave redundant, writes its 4 c) ----
    {
        float av[NC];
        float mx = -1e30f;
#pragma unroll
        for (int c = 0; c < NC; c++) { av[c] = aSm[c * 64 + lane]; mx = fmaxf(mx, av[c]); }
        float ssum = 0.f;
#pragma unroll
        for (int c = 0; c < NC; c++) { av[c] = __expf(av[c] - mx); ssum += av[c]; }
        const float inv = 1.f / ssum;
#pragma unroll
        for (int cc = 0; cc < 4; cc++) cwSm[(wave * 4 + cc) * 64 + lane] = av[wave * 4 + cc] * inv;
    }
    __syncthreads();
    // ---- phase 3: wave g takes rows g*16..g*16+15, lane = i ----
    float acc[NC];
#pragma unroll
    for (int c = 0; c < NC; c++) acc[c] = 0.f;
#pragma unroll 4
    for (int t2 = 0; t2 < 16; t2++) {
        const int np = wave * 16 + t2;
        const float xv = xT[lane * 64 + ((np + lane) & 63)];
#pragma unroll
        for (int c = 0; c < NC; c++) acc[c] += cwSm[c * 64 + np] * xv;
    }
    __syncthreads();                      // last xT read done; safe to alias
    float* pSm = xT;                      // [4][16][64]
#pragma unroll
    for (int c = 0; c < NC; c++) pSm[(wave * NC + c) * 64 + lane] = acc[c];
    __syncthreads();
    // ---- in-block reduce over 4 waves, store one partial per block ----
    for (int o = tid; o < NC * 64; o += 256) {
        const float s2 = pSm[o] + pSm[NC * 64 + o] + pSm[2 * NC * 64 + o] + pSm[3 * NC * 64 + o];
        partOut[((size_t)(b * 16 + chunk) * NC) * 64 + o] = s2;
    }
}

// -------- Kernel 4: final reduce + squash -> output v [64][16][32]
__global__ __launch_bounds__(256) void k_capsF(const float* __restrict__ partIn,
                                               const float* __restrict__ W,
                                               float* __restrict__ out) {
    const int b = blockIdx.x, tid = threadIdx.x;
    __shared__ float redSm[NC * 64];
    for (int o = tid; o < NC * 64; o += 256) {
        float r = 0.f;
#pragma unroll
        for (int k = 0; k < 16; k++) r += partIn[((size_t)(b * 16 + k) * NC) * 64 + o];
        redSm[o] = r;
    }
    __syncthreads();
    const int d = tid & 31, cg = tid >> 5;
#pragma unroll
    for (int h = 0; h < 2; h++) {
        const int c = cg + h * 8;
        const float* Wc = W + c * IDIM * DC;
        float s = 0.f;
#pragma unroll 8
        for (int i = 0; i < IDIM; i++) s += redSm[c * 64 + i] * Wc[i * DC + d];
        float n2 = s * s;
#pragma unroll
        for (int m = 16; m >= 1; m >>= 1) n2 += __shfl_xor(n2, m);
        const float nr = sqrtf(n2);
        out[(b * NC + c) * DC + d] = (n2 / (1.f + n2)) * s / (nr + 1e-8f);
    }
}

extern "C" void kernel_launch(void* const* d_in, const int* in_sizes, int n_in,
                              void* d_out, int out_size, void* d_ws, size_t ws_size,
                              hipStream_t stream) {
    const float* x = (const float*)d_in[0];    // [64,1024,64]
    const float* W = (const float*)d_in[1];    // [16,64,32]
    float* out = (float*)d_out;                // [64,16,32]
    float* ws = (float*)d_ws;

    float* xsump = ws + WS_XSUMP;
    float* xs1p  = ws + WS_XS1P;
    float* xs2p  = ws + WS_XS2P;
    float* blog  = ws + WS_BLOG;

    // iter 0 colsum partials
    k_colsum<<<dim3(8, B_SZ), 256, 0, stream>>>(x, xsump);
    // iter 1: fused {caps0 from xsump} + routing -> blog, xs1 partials
    k_route<1><<<dim3(16, B_SZ), 256, 0, stream>>>(x, W, xsump, blog, xs1p);
    // iter 2: fused {caps1 from xs1p} + routing (blog += a) -> xs2 partials
    k_route<2><<<dim3(16, B_SZ), 256, 0, stream>>>(x, W, xs1p, blog, xs2p);
    // final squash -> output
    k_capsF<<<B_SZ, 256, 0, stream>>>(xs2p, W, out);
}